// Round 1
// baseline (1048.715 us; speedup 1.0000x reference)
//
#include <hip/hip_runtime.h>
#include <hip/hip_bf16.h>

#define B_ 32
#define S_ 1024
#define D_ 512
#define PSTR 1032   // P-lds row stride in bf16 elems (1024 + 8 pad)

typedef __attribute__((ext_vector_type(8))) short short8;
typedef __attribute__((ext_vector_type(4))) float f32x4;

__device__ __forceinline__ unsigned short f2bf(float f) {
    unsigned u = __float_as_uint(f);
    u += 0x7FFFu + ((u >> 16) & 1u);   // round-to-nearest-even
    return (unsigned short)(u >> 16);
}
__device__ __forceinline__ float bf2f(unsigned short s) {
    return __uint_as_float(((unsigned)s) << 16);
}

__global__ __launch_bounds__(256, 3)
void attn_fused(const float* __restrict__ Q, const float* __restrict__ K,
                const float* __restrict__ V, const int* __restrict__ RM,
                float* __restrict__ Out, float* __restrict__ Attn) {
    // LDS: P scores 16 x PSTR bf16 (33024 B) + Vt 4096 dwords (16384 B)
    __shared__ short p_lds[16 * PSTR];
    __shared__ short vt_lds[8192];
    float* rm_f = reinterpret_cast<float*>(vt_lds);   // overlay, dead before Vt use

    const int tid  = threadIdx.x;
    const int lane = tid & 63;
    const int w    = tid >> 6;        // wave 0..3
    const int m    = lane & 15;
    const int quad = lane >> 4;

    // XCD-aware swizzle: consecutive work on one XCD shares a batch's K/V in L2
    const int work = ((int)blockIdx.x & 7) * 256 + ((int)blockIdx.x >> 3);
    const int b  = work >> 6;
    const int qt = work & 63;

    // stage rep_mask as float (lives in vt_lds region; consumed in softmax)
    {
        const int4 mi = *reinterpret_cast<const int4*>(RM + b * S_ + tid * 4);
        float4 mf = make_float4((float)mi.x, (float)mi.y, (float)mi.z, (float)mi.w);
        *reinterpret_cast<float4*>(&rm_f[tid * 4]) = mf;
    }

    // ---------------- Phase 1: raw scores = Q K^T (bf16 MFMA) ----------------
    f32x4 acc1[16];
    #pragma unroll
    for (int t = 0; t < 16; ++t) acc1[t] = (f32x4){0.f, 0.f, 0.f, 0.f};

    const int kw0 = w * 256;   // this wave's k-column base
    const float* qbase = Q + ((size_t)(b * S_ + qt * 16 + m)) * D_ + quad * 8;
    const float* kbase = K + ((size_t)(b * S_ + kw0 + m)) * D_ + quad * 8;

    for (int ds = 0; ds < 16; ++ds) {               // d in chunks of 32
        const float4 qa = *reinterpret_cast<const float4*>(qbase + ds * 32);
        const float4 qb = *reinterpret_cast<const float4*>(qbase + ds * 32 + 4);
        short8 af;
        af[0]=(short)f2bf(qa.x); af[1]=(short)f2bf(qa.y); af[2]=(short)f2bf(qa.z); af[3]=(short)f2bf(qa.w);
        af[4]=(short)f2bf(qb.x); af[5]=(short)f2bf(qb.y); af[6]=(short)f2bf(qb.z); af[7]=(short)f2bf(qb.w);
        #pragma unroll
        for (int t = 0; t < 16; ++t) {
            const float* kr = kbase + (size_t)t * 16 * D_ + ds * 32;
            const float4 ka = *reinterpret_cast<const float4*>(kr);
            const float4 kb = *reinterpret_cast<const float4*>(kr + 4);
            short8 bf;
            bf[0]=(short)f2bf(ka.x); bf[1]=(short)f2bf(ka.y); bf[2]=(short)f2bf(ka.z); bf[3]=(short)f2bf(ka.w);
            bf[4]=(short)f2bf(kb.x); bf[5]=(short)f2bf(kb.y); bf[6]=(short)f2bf(kb.z); bf[7]=(short)f2bf(kb.w);
            acc1[t] = __builtin_amdgcn_mfma_f32_16x16x32_bf16(af, bf, acc1[t], 0, 0, 0);
        }
    }
    // C/D layout (verified m89/m91): col = lane&15, row = quad*4 + reg
    #pragma unroll
    for (int t = 0; t < 16; ++t) {
        const int col = kw0 + t * 16 + m;
        #pragma unroll
        for (int r = 0; r < 4; ++r)
            p_lds[(quad * 4 + r) * PSTR + col] = (short)f2bf(acc1[t][r]);
    }
    __syncthreads();

    // ---------------- softmax (reference-faithful masked variant) ----------------
    {
        const int r  = tid >> 4;          // q row 0..15
        const int kc = tid & 15;
        const int qg = qt * 16 + r;       // global q index
        const float rmq = rm_f[qg];
        const float inv_scale = 0.04419417382415922f;   // 1/sqrt(512)

        float4 sv[16];
        float mx = 0.0f;                  // masked_vec includes zeros -> max >= 0
        #pragma unroll
        for (int j = 0; j < 16; ++j) {
            const int k0 = 4 * kc + 64 * j;
            short4 s4 = *reinterpret_cast<const short4*>(&p_lds[r * PSTR + k0]);
            float s0 = bf2f((unsigned short)s4.x) * inv_scale;
            float s1 = bf2f((unsigned short)s4.y) * inv_scale;
            float s2 = bf2f((unsigned short)s4.z) * inv_scale;
            float s3 = bf2f((unsigned short)s4.w) * inv_scale;
            sv[j] = make_float4(s0, s1, s2, s3);
            if (rmq != 0.f) {
                if (rm_f[k0+0] != 0.f && (k0+0) < qg) mx = fmaxf(mx, s0);
                if (rm_f[k0+1] != 0.f && (k0+1) < qg) mx = fmaxf(mx, s1);
                if (rm_f[k0+2] != 0.f && (k0+2) < qg) mx = fmaxf(mx, s2);
                if (rm_f[k0+3] != 0.f && (k0+3) < qg) mx = fmaxf(mx, s3);
            }
        }
        #pragma unroll
        for (int off = 1; off < 16; off <<= 1) mx = fmaxf(mx, __shfl_xor(mx, off));

        float sum = 0.0f;
        #pragma unroll
        for (int j = 0; j < 16; ++j) {
            const int k0 = 4 * kc + 64 * j;
            float p0 = 0.f, p1 = 0.f, p2 = 0.f, p3 = 0.f;
            if (rmq != 0.f) {
                if (rm_f[k0+0] != 0.f && (k0+0) < qg) p0 = __expf(sv[j].x - mx);
                if (rm_f[k0+1] != 0.f && (k0+1) < qg) p1 = __expf(sv[j].y - mx);
                if (rm_f[k0+2] != 0.f && (k0+2) < qg) p2 = __expf(sv[j].z - mx);
                if (rm_f[k0+3] != 0.f && (k0+3) < qg) p3 = __expf(sv[j].w - mx);
            }
            sv[j] = make_float4(p0, p1, p2, p3);
            sum += (p0 + p1) + (p2 + p3);
        }
        #pragma unroll
        for (int off = 1; off < 16; off <<= 1) sum += __shfl_xor(sum, off);

        float den = sum + ((sum == 0.0f) ? 1.0f : 0.0f);
        const float invd = 1.0f / (den + 1e-20f);

        float* arow = Attn + ((size_t)(b * S_) + qg) * S_;
        #pragma unroll
        for (int j = 0; j < 16; ++j) {
            const int k0 = 4 * kc + 64 * j;
            float p0 = sv[j].x * invd, p1 = sv[j].y * invd;
            float p2 = sv[j].z * invd, p3 = sv[j].w * invd;
            *reinterpret_cast<float4*>(arow + k0) = make_float4(p0, p1, p2, p3);
            short4 pb;
            pb.x=(short)f2bf(p0); pb.y=(short)f2bf(p1); pb.z=(short)f2bf(p2); pb.w=(short)f2bf(p3);
            *reinterpret_cast<short4*>(&p_lds[r * PSTR + k0]) = pb;
        }
    }
    __syncthreads();   // P now holds normalized bf16 probs

    // ---------------- Phase 2: Out = P V (bf16 MFMA, V transposed via LDS) ----------------
    f32x4 acc2[8];
    #pragma unroll
    for (int i = 0; i < 8; ++i) acc2[i] = (f32x4){0.f, 0.f, 0.f, 0.f};

    for (int kk = 0; kk < 32; ++kk) {               // contraction chunk of 32 keys
        const short8 af = *reinterpret_cast<const short8*>(
            &p_lds[m * PSTR + kk * 32 + quad * 8]);
        #pragma unroll
        for (int nh = 0; nh < 2; ++nh) {            // d-column half (256 each)
            __syncthreads();
            // stage Vt: [n_local 0..255][k_local 0..31] bf16, XOR-swizzled 4-dw blocks
            {
                const int nl0 = tid & 63;
                const int qq0 = tid >> 6;
                #pragma unroll
                for (int i = 0; i < 8; ++i) {
                    const int nl = nl0 + 64 * (i & 3);
                    const int qq = qq0 + 4 * (i >> 2);     // k-quad 0..7
                    const float* src = V + ((size_t)(b * S_ + kk * 32 + qq * 4)) * D_
                                         + nh * 256 + nl;
                    const float v0 = src[0];
                    const float v1 = src[D_];
                    const float v2 = src[2 * D_];
                    const float v3 = src[3 * D_];
                    const int g  = (nl >> 1) & 3;
                    const int dw = nl * 16 + 4 * ((qq >> 1) ^ g) + 2 * (qq & 1);
                    short4 pk;
                    pk.x=(short)f2bf(v0); pk.y=(short)f2bf(v1);
                    pk.z=(short)f2bf(v2); pk.w=(short)f2bf(v3);
                    *reinterpret_cast<short4*>(&vt_lds[dw * 2]) = pk;
                }
            }
            __syncthreads();
            #pragma unroll
            for (int f = 0; f < 4; ++f) {
                const int nloc = (w + 4 * f) * 16 + m;     // local n within half
                const int g  = (nloc >> 1) & 3;
                const int dw = nloc * 16 + 4 * (quad ^ g);
                const short8 bf = *reinterpret_cast<const short8*>(&vt_lds[dw * 2]);
                acc2[nh * 4 + f] = __builtin_amdgcn_mfma_f32_16x16x32_bf16(af, bf, acc2[nh * 4 + f], 0, 0, 0);
            }
        }
    }

    float* obase = Out + ((size_t)(b * S_ + qt * 16)) * D_;
    #pragma unroll
    for (int nh = 0; nh < 2; ++nh) {
        #pragma unroll
        for (int f = 0; f < 4; ++f) {
            const int n0 = nh * 256 + (w + 4 * f) * 16 + m;
            #pragma unroll
            for (int r = 0; r < 4; ++r)
                obase[(size_t)(quad * 4 + r) * D_ + n0] = acc2[nh * 4 + f][r];
        }
    }
}

extern "C" void kernel_launch(void* const* d_in, const int* in_sizes, int n_in,
                              void* d_out, int out_size, void* d_ws, size_t ws_size,
                              hipStream_t stream) {
    (void)in_sizes; (void)n_in; (void)d_ws; (void)ws_size; (void)out_size;
    const float* q  = (const float*)d_in[0];
    const float* k  = (const float*)d_in[1];
    const float* v  = (const float*)d_in[2];
    const int*   rm = (const int*)d_in[3];
    float* out  = (float*)d_out;
    float* attn = out + (size_t)B_ * S_ * D_;   // outputs concatenated: out, attn_sm
    attn_fused<<<dim3(B_ * (S_ / 16)), dim3(256), 0, stream>>>(q, k, v, rm, out, attn);
}

// Round 2
// 624.558 us; speedup vs baseline: 1.6791x; 1.6791x over previous
//
#include <hip/hip_runtime.h>
#include <hip/hip_bf16.h>

#define B_ 32
#define S_ 1024
#define D_ 512
#define PSTR 1048    // main-kernel P row stride (bf16): 524 dw, m*12%32 -> max 2-way (free)
#define PSTR1 1032   // fallback v1 stride

typedef __attribute__((ext_vector_type(8))) short short8;
typedef __attribute__((ext_vector_type(4))) float f32x4;

__device__ __forceinline__ unsigned short f2bf(float f) {
    unsigned u = __float_as_uint(f);
    u += 0x7FFFu + ((u >> 16) & 1u);   // round-to-nearest-even
    return (unsigned short)(u >> 16);
}
__device__ __forceinline__ float bf2f(unsigned short s) {
    return __uint_as_float(((unsigned)s) << 16);
}

// ===================== prep: K -> KT bf16, fragment-native =====================
// KT[b][ds(16)][kcol(1024)][dquad(4)][8]  (elem addr = ((ds*1024+kcol)*4+dquad)*8)
// Phase-1 B-frag for (ds, tile): lane(m,quad) reads 16B at kcol=t*16+m, dquad=quad
// -> 2KB contiguous per wave instruction.
__global__ __launch_bounds__(256) void prep_k(const float* __restrict__ K,
                                              unsigned short* __restrict__ KT) {
    const int blk = blockIdx.x;          // 32*256 blocks: 4 rows x 512 d each
    const int b  = blk >> 8;
    const int r4 = blk & 255;
    const int t  = threadIdx.x;
    const int r  = t >> 6;               // 0..3
    const int d0 = (t & 63) * 8;
    const int s  = r4 * 4 + r;
    const float* src = K + ((size_t)(b * S_ + s)) * D_ + d0;
    const float4 a = *reinterpret_cast<const float4*>(src);
    const float4 c = *reinterpret_cast<const float4*>(src + 4);
    const int ds = d0 >> 5, dq = (d0 >> 3) & 3;
    short8 p;
    p[0]=(short)f2bf(a.x); p[1]=(short)f2bf(a.y); p[2]=(short)f2bf(a.z); p[3]=(short)f2bf(a.w);
    p[4]=(short)f2bf(c.x); p[5]=(short)f2bf(c.y); p[6]=(short)f2bf(c.z); p[7]=(short)f2bf(c.w);
    unsigned short* dst = KT + (size_t)b * 524288 + (((ds * 1024 + s) * 4 + dq) * 8);
    *reinterpret_cast<short8*>(dst) = p;
}

// ===================== prep: V -> VT bf16, transposed fragment-native =====================
// VT[b][kk(32)][dcol(512)][kquad(4)][8]  (elem addr = ((kk*512+dcol)*4+kquad)*8)
// Phase-2 B-frag for (kk, tile): lane(m,quad) reads 16B at dcol=tile*16+m, kquad=quad
// -> 2KB contiguous per wave instruction.
__global__ __launch_bounds__(256) void prep_v(const float* __restrict__ V,
                                              unsigned short* __restrict__ VT) {
    __shared__ float st[32 * 260];       // 32 s-rows x 256 d (+pad not needed; col reads are lane-major)
    const int blk = blockIdx.x;          // 32*32*2 blocks: [32 s x 256 d] tiles
    const int b  = blk >> 6;
    const int kk = (blk >> 1) & 31;
    const int dh = blk & 1;
    const int t  = threadIdx.x;
    const int r0 = t >> 6;               // 0..3
    const int c4 = (t & 63) * 4;
    #pragma unroll
    for (int p = 0; p < 8; ++p) {
        const int s = r0 + p * 4;
        const float4 val = *reinterpret_cast<const float4*>(
            V + ((size_t)(b * S_ + kk * 32 + s)) * D_ + dh * 256 + c4);
        *reinterpret_cast<float4*>(&st[s * 260 + c4]) = val;
    }
    __syncthreads();
    const int dcol = t;                  // local 0..255
    unsigned short* dst = VT + (size_t)b * 524288 + ((kk * 512 + dh * 256 + dcol) * 4) * 8;
    #pragma unroll
    for (int kq = 0; kq < 4; ++kq) {
        short8 p;
        #pragma unroll
        for (int j = 0; j < 8; ++j) p[j] = (short)f2bf(st[(kq * 8 + j) * 260 + dcol]);
        *reinterpret_cast<short8*>(dst + kq * 8) = p;
    }
}

// ===================== main fused kernel =====================
__global__ __launch_bounds__(256, 4)
void attn_main(const float* __restrict__ Q, const unsigned short* __restrict__ KT,
               const unsigned short* __restrict__ VT, const int* __restrict__ RM,
               float* __restrict__ Out, float* __restrict__ Attn) {
    __shared__ short p_lds[16 * PSTR];   // 33536 B
    __shared__ float rm_f[1024];         // 4096 B

    const int tid  = threadIdx.x;
    const int lane = tid & 63;
    const int w    = tid >> 6;
    const int m    = lane & 15;
    const int quad = lane >> 4;

    const int work = ((int)blockIdx.x & 7) * 256 + ((int)blockIdx.x >> 3);
    const int b  = work >> 6;
    const int qt = work & 63;

    {
        const int4 mi = *reinterpret_cast<const int4*>(RM + b * S_ + tid * 4);
        float4 mf = make_float4((float)mi.x, (float)mi.y, (float)mi.z, (float)mi.w);
        *reinterpret_cast<float4*>(&rm_f[tid * 4]) = mf;
    }

    // ---------------- Phase 1: raw scores = Q K^T ----------------
    f32x4 acc1[16];
    #pragma unroll
    for (int t = 0; t < 16; ++t) acc1[t] = (f32x4){0.f, 0.f, 0.f, 0.f};

    const int kw0 = w * 256;
    const float* qbase = Q + ((size_t)(b * S_ + qt * 16 + m)) * D_ + quad * 8;
    const unsigned short* kb = KT + (size_t)b * 524288 + (kw0 + m) * 32 + quad * 8;

    for (int ds = 0; ds < 16; ++ds) {
        const float4 qa = *reinterpret_cast<const float4*>(qbase + ds * 32);
        const float4 qb = *reinterpret_cast<const float4*>(qbase + ds * 32 + 4);
        short8 af;
        af[0]=(short)f2bf(qa.x); af[1]=(short)f2bf(qa.y); af[2]=(short)f2bf(qa.z); af[3]=(short)f2bf(qa.w);
        af[4]=(short)f2bf(qb.x); af[5]=(short)f2bf(qb.y); af[6]=(short)f2bf(qb.z); af[7]=(short)f2bf(qb.w);
        const unsigned short* kds = kb + ds * 32768;
        #pragma unroll
        for (int t = 0; t < 16; ++t) {
            const short8 bf = *reinterpret_cast<const short8*>(kds + t * 512);
            acc1[t] = __builtin_amdgcn_mfma_f32_16x16x32_bf16(af, bf, acc1[t], 0, 0, 0);
        }
    }
    #pragma unroll
    for (int t = 0; t < 16; ++t) {
        const int col = kw0 + t * 16 + m;
        #pragma unroll
        for (int r = 0; r < 4; ++r)
            p_lds[(quad * 4 + r) * PSTR + col] = (short)f2bf(acc1[t][r]);
    }
    __syncthreads();

    // ---------------- softmax (reference-faithful masked variant) ----------------
    {
        const int r  = tid >> 4;
        const int kc = tid & 15;
        const int qg = qt * 16 + r;
        const float rmq = rm_f[qg];
        const float inv_scale = 0.04419417382415922f;   // 1/sqrt(512)

        float4 sv[16];
        float mx = 0.0f;
        #pragma unroll
        for (int j = 0; j < 16; ++j) {
            const int k0 = 4 * kc + 64 * j;
            short4 s4 = *reinterpret_cast<const short4*>(&p_lds[r * PSTR + k0]);
            const float4 rmk = *reinterpret_cast<const float4*>(&rm_f[k0]);
            float s0 = bf2f((unsigned short)s4.x) * inv_scale;
            float s1 = bf2f((unsigned short)s4.y) * inv_scale;
            float s2 = bf2f((unsigned short)s4.z) * inv_scale;
            float s3 = bf2f((unsigned short)s4.w) * inv_scale;
            sv[j] = make_float4(s0, s1, s2, s3);
            if (rmq != 0.f) {
                if (rmk.x != 0.f && (k0+0) < qg) mx = fmaxf(mx, s0);
                if (rmk.y != 0.f && (k0+1) < qg) mx = fmaxf(mx, s1);
                if (rmk.z != 0.f && (k0+2) < qg) mx = fmaxf(mx, s2);
                if (rmk.w != 0.f && (k0+3) < qg) mx = fmaxf(mx, s3);
            }
        }
        #pragma unroll
        for (int off = 1; off < 16; off <<= 1) mx = fmaxf(mx, __shfl_xor(mx, off));

        float sum = 0.0f;
        #pragma unroll
        for (int j = 0; j < 16; ++j) {
            const int k0 = 4 * kc + 64 * j;
            const float4 rmk = *reinterpret_cast<const float4*>(&rm_f[k0]);
            float p0 = 0.f, p1 = 0.f, p2 = 0.f, p3 = 0.f;
            if (rmq != 0.f) {
                if (rmk.x != 0.f && (k0+0) < qg) p0 = __expf(sv[j].x - mx);
                if (rmk.y != 0.f && (k0+1) < qg) p1 = __expf(sv[j].y - mx);
                if (rmk.z != 0.f && (k0+2) < qg) p2 = __expf(sv[j].z - mx);
                if (rmk.w != 0.f && (k0+3) < qg) p3 = __expf(sv[j].w - mx);
            }
            sv[j] = make_float4(p0, p1, p2, p3);
            sum += (p0 + p1) + (p2 + p3);
        }
        #pragma unroll
        for (int off = 1; off < 16; off <<= 1) sum += __shfl_xor(sum, off);

        float den = sum + ((sum == 0.0f) ? 1.0f : 0.0f);
        const float invd = 1.0f / (den + 1e-20f);

        float* arow = Attn + ((size_t)(b * S_) + qg) * S_;
        #pragma unroll
        for (int j = 0; j < 16; ++j) {
            const int k0 = 4 * kc + 64 * j;
            float p0 = sv[j].x * invd, p1 = sv[j].y * invd;
            float p2 = sv[j].z * invd, p3 = sv[j].w * invd;
            *reinterpret_cast<float4*>(arow + k0) = make_float4(p0, p1, p2, p3);
            short4 pb;
            pb.x=(short)f2bf(p0); pb.y=(short)f2bf(p1); pb.z=(short)f2bf(p2); pb.w=(short)f2bf(p3);
            *reinterpret_cast<short4*>(&p_lds[r * PSTR + k0]) = pb;
        }
    }
    __syncthreads();

    // ---------------- Phase 2: Out = P V (B-frags straight from global VT) ----------------
    f32x4 acc2[8];
    #pragma unroll
    for (int i = 0; i < 8; ++i) acc2[i] = (f32x4){0.f, 0.f, 0.f, 0.f};

    const unsigned short* vb = VT + (size_t)b * 524288 + m * 32 + quad * 8;
    for (int kk = 0; kk < 32; ++kk) {
        const short8 af = *reinterpret_cast<const short8*>(
            &p_lds[m * PSTR + kk * 32 + quad * 8]);
        const unsigned short* vkk = vb + kk * 16384;
        #pragma unroll
        for (int f = 0; f < 8; ++f) {
            const int dtile = f * 4 + w;
            const short8 bf = *reinterpret_cast<const short8*>(vkk + dtile * 512);
            acc2[f] = __builtin_amdgcn_mfma_f32_16x16x32_bf16(af, bf, acc2[f], 0, 0, 0);
        }
    }

    float* obase = Out + ((size_t)(b * S_ + qt * 16)) * D_;
    #pragma unroll
    for (int f = 0; f < 8; ++f) {
        const int n0 = (f * 4 + w) * 16 + m;
        #pragma unroll
        for (int r = 0; r < 4; ++r)
            obase[(size_t)(quad * 4 + r) * D_ + n0] = acc2[f][r];
    }
}

// ===================== fallback v1 (used only if ws too small) =====================
__global__ __launch_bounds__(256, 3)
void attn_fused_v1(const float* __restrict__ Q, const float* __restrict__ K,
                   const float* __restrict__ V, const int* __restrict__ RM,
                   float* __restrict__ Out, float* __restrict__ Attn) {
    __shared__ short p_lds[16 * PSTR1];
    __shared__ short vt_lds[8192];
    float* rm_f = reinterpret_cast<float*>(vt_lds);

    const int tid  = threadIdx.x;
    const int lane = tid & 63;
    const int w    = tid >> 6;
    const int m    = lane & 15;
    const int quad = lane >> 4;

    const int work = ((int)blockIdx.x & 7) * 256 + ((int)blockIdx.x >> 3);
    const int b  = work >> 6;
    const int qt = work & 63;

    {
        const int4 mi = *reinterpret_cast<const int4*>(RM + b * S_ + tid * 4);
        float4 mf = make_float4((float)mi.x, (float)mi.y, (float)mi.z, (float)mi.w);
        *reinterpret_cast<float4*>(&rm_f[tid * 4]) = mf;
    }

    f32x4 acc1[16];
    #pragma unroll
    for (int t = 0; t < 16; ++t) acc1[t] = (f32x4){0.f, 0.f, 0.f, 0.f};

    const int kw0 = w * 256;
    const float* qbase = Q + ((size_t)(b * S_ + qt * 16 + m)) * D_ + quad * 8;
    const float* kbase = K + ((size_t)(b * S_ + kw0 + m)) * D_ + quad * 8;

    for (int ds = 0; ds < 16; ++ds) {
        const float4 qa = *reinterpret_cast<const float4*>(qbase + ds * 32);
        const float4 qb = *reinterpret_cast<const float4*>(qbase + ds * 32 + 4);
        short8 af;
        af[0]=(short)f2bf(qa.x); af[1]=(short)f2bf(qa.y); af[2]=(short)f2bf(qa.z); af[3]=(short)f2bf(qa.w);
        af[4]=(short)f2bf(qb.x); af[5]=(short)f2bf(qb.y); af[6]=(short)f2bf(qb.z); af[7]=(short)f2bf(qb.w);
        #pragma unroll
        for (int t = 0; t < 16; ++t) {
            const float* kr = kbase + (size_t)t * 16 * D_ + ds * 32;
            const float4 ka = *reinterpret_cast<const float4*>(kr);
            const float4 kb = *reinterpret_cast<const float4*>(kr + 4);
            short8 bf;
            bf[0]=(short)f2bf(ka.x); bf[1]=(short)f2bf(ka.y); bf[2]=(short)f2bf(ka.z); bf[3]=(short)f2bf(ka.w);
            bf[4]=(short)f2bf(kb.x); bf[5]=(short)f2bf(kb.y); bf[6]=(short)f2bf(kb.z); bf[7]=(short)f2bf(kb.w);
            acc1[t] = __builtin_amdgcn_mfma_f32_16x16x32_bf16(af, bf, acc1[t], 0, 0, 0);
        }
    }
    #pragma unroll
    for (int t = 0; t < 16; ++t) {
        const int col = kw0 + t * 16 + m;
        #pragma unroll
        for (int r = 0; r < 4; ++r)
            p_lds[(quad * 4 + r) * PSTR1 + col] = (short)f2bf(acc1[t][r]);
    }
    __syncthreads();

    {
        const int r  = tid >> 4;
        const int kc = tid & 15;
        const int qg = qt * 16 + r;
        const float rmq = rm_f[qg];
        const float inv_scale = 0.04419417382415922f;

        float4 sv[16];
        float mx = 0.0f;
        #pragma unroll
        for (int j = 0; j < 16; ++j) {
            const int k0 = 4 * kc + 64 * j;
            short4 s4 = *reinterpret_cast<const short4*>(&p_lds[r * PSTR1 + k0]);
            float s0 = bf2f((unsigned short)s4.x) * inv_scale;
            float s1 = bf2f((unsigned short)s4.y) * inv_scale;
            float s2 = bf2f((unsigned short)s4.z) * inv_scale;
            float s3 = bf2f((unsigned short)s4.w) * inv_scale;
            sv[j] = make_float4(s0, s1, s2, s3);
            if (rmq != 0.f) {
                if (rm_f[k0+0] != 0.f && (k0+0) < qg) mx = fmaxf(mx, s0);
                if (rm_f[k0+1] != 0.f && (k0+1) < qg) mx = fmaxf(mx, s1);
                if (rm_f[k0+2] != 0.f && (k0+2) < qg) mx = fmaxf(mx, s2);
                if (rm_f[k0+3] != 0.f && (k0+3) < qg) mx = fmaxf(mx, s3);
            }
        }
        #pragma unroll
        for (int off = 1; off < 16; off <<= 1) mx = fmaxf(mx, __shfl_xor(mx, off));

        float sum = 0.0f;
        #pragma unroll
        for (int j = 0; j < 16; ++j) {
            const int k0 = 4 * kc + 64 * j;
            float p0 = 0.f, p1 = 0.f, p2 = 0.f, p3 = 0.f;
            if (rmq != 0.f) {
                if (rm_f[k0+0] != 0.f && (k0+0) < qg) p0 = __expf(sv[j].x - mx);
                if (rm_f[k0+1] != 0.f && (k0+1) < qg) p1 = __expf(sv[j].y - mx);
                if (rm_f[k0+2] != 0.f && (k0+2) < qg) p2 = __expf(sv[j].z - mx);
                if (rm_f[k0+3] != 0.f && (k0+3) < qg) p3 = __expf(sv[j].w - mx);
            }
            sv[j] = make_float4(p0, p1, p2, p3);
            sum += (p0 + p1) + (p2 + p3);
        }
        #pragma unroll
        for (int off = 1; off < 16; off <<= 1) sum += __shfl_xor(sum, off);

        float den = sum + ((sum == 0.0f) ? 1.0f : 0.0f);
        const float invd = 1.0f / (den + 1e-20f);

        float* arow = Attn + ((size_t)(b * S_) + qg) * S_;
        #pragma unroll
        for (int j = 0; j < 16; ++j) {
            const int k0 = 4 * kc + 64 * j;
            float p0 = sv[j].x * invd, p1 = sv[j].y * invd;
            float p2 = sv[j].z * invd, p3 = sv[j].w * invd;
            *reinterpret_cast<float4*>(arow + k0) = make_float4(p0, p1, p2, p3);
            short4 pb;
            pb.x=(short)f2bf(p0); pb.y=(short)f2bf(p1); pb.z=(short)f2bf(p2); pb.w=(short)f2bf(p3);
            *reinterpret_cast<short4*>(&p_lds[r * PSTR1 + k0]) = pb;
        }
    }
    __syncthreads();

    f32x4 acc2[8];
    #pragma unroll
    for (int i = 0; i < 8; ++i) acc2[i] = (f32x4){0.f, 0.f, 0.f, 0.f};

    for (int kk = 0; kk < 32; ++kk) {
        const short8 af = *reinterpret_cast<const short8*>(
            &p_lds[m * PSTR1 + kk * 32 + quad * 8]);
        #pragma unroll
        for (int nh = 0; nh < 2; ++nh) {
            __syncthreads();
            {
                const int nl0 = tid & 63;
                const int qq0 = tid >> 6;
                #pragma unroll
                for (int i = 0; i < 8; ++i) {
                    const int nl = nl0 + 64 * (i & 3);
                    const int qq = qq0 + 4 * (i >> 2);
                    const float* src = V + ((size_t)(b * S_ + kk * 32 + qq * 4)) * D_
                                         + nh * 256 + nl;
                    const float v0 = src[0];
                    const float v1 = src[D_];
                    const float v2 = src[2 * D_];
                    const float v3 = src[3 * D_];
                    const int g  = (nl >> 1) & 3;
                    const int dw = nl * 16 + 4 * ((qq >> 1) ^ g) + 2 * (qq & 1);
                    short4 pk;
                    pk.x=(short)f2bf(v0); pk.y=(short)f2bf(v1);
                    pk.z=(short)f2bf(v2); pk.w=(short)f2bf(v3);
                    *reinterpret_cast<short4*>(&vt_lds[dw * 2]) = pk;
                }
            }
            __syncthreads();
            #pragma unroll
            for (int f = 0; f < 4; ++f) {
                const int nloc = (w + 4 * f) * 16 + m;
                const int g  = (nloc >> 1) & 3;
                const int dw = nloc * 16 + 4 * (quad ^ g);
                const short8 bf = *reinterpret_cast<const short8*>(&vt_lds[dw * 2]);
                acc2[nh * 4 + f] = __builtin_amdgcn_mfma_f32_16x16x32_bf16(af, bf, acc2[nh * 4 + f], 0, 0, 0);
            }
        }
    }

    float* obase = Out + ((size_t)(b * S_ + qt * 16)) * D_;
    #pragma unroll
    for (int nh = 0; nh < 2; ++nh) {
        #pragma unroll
        for (int f = 0; f < 4; ++f) {
            const int n0 = nh * 256 + (w + 4 * f) * 16 + m;
            #pragma unroll
            for (int r = 0; r < 4; ++r)
                obase[(size_t)(quad * 4 + r) * D_ + n0] = acc2[nh * 4 + f][r];
        }
    }
}

extern "C" void kernel_launch(void* const* d_in, const int* in_sizes, int n_in,
                              void* d_out, int out_size, void* d_ws, size_t ws_size,
                              hipStream_t stream) {
    (void)in_sizes; (void)n_in; (void)out_size;
    const float* q  = (const float*)d_in[0];
    const float* k  = (const float*)d_in[1];
    const float* v  = (const float*)d_in[2];
    const int*   rm = (const int*)d_in[3];
    float* out  = (float*)d_out;
    float* attn = out + (size_t)B_ * S_ * D_;

    const size_t kt_bytes = (size_t)B_ * 524288 * 2;   // 32 MB
    const size_t need = 2 * kt_bytes;                  // KT + VT = 64 MB
    if (ws_size >= need) {
        unsigned short* KT = (unsigned short*)d_ws;
        unsigned short* VT = KT + (size_t)B_ * 524288;
        prep_k<<<dim3(B_ * 256), dim3(256), 0, stream>>>(k, KT);
        prep_v<<<dim3(B_ * 64), dim3(256), 0, stream>>>(v, VT);
        attn_main<<<dim3(B_ * (S_ / 16)), dim3(256), 0, stream>>>(q, KT, VT, rm, out, attn);
    } else {
        attn_fused_v1<<<dim3(B_ * (S_ / 16)), dim3(256), 0, stream>>>(q, k, v, rm, out, attn);
    }
}